// Round 8
// baseline (493.683 us; speedup 1.0000x reference)
//
#include <hip/hip_runtime.h>

// GCN 2-layer + mean-pool + linear head, f32.
// Round 8: agg was traffic-bound (FETCH 425MB vs 51MB working set).
//   - gemm epilogue pre-scales rows by dis: h' = dis*h. Removes per-edge
//     dis[src] gather + shfl + fma; inner loop is pure adds.
//   - agg outputs stored non-temporal (don't evict h' from cache);
//     col loaded non-temporal.
//   - gather batch deepened to 16.
// GEMMs (fragment-packed MFMA split-bf16), scan, CSR build, pool unchanged.

#define NN 100000
#define NG 128
#define SCHUNK 1024

typedef __attribute__((ext_vector_type(8))) short short8;
typedef __attribute__((ext_vector_type(4))) float f32x4;

__device__ __forceinline__ unsigned short f2bf(float f) {
    union { float f; unsigned u; } v; v.f = f;
    unsigned r = v.u + 0x7fffu + ((v.u >> 16) & 1u);  // round-nearest-even
    return (unsigned short)(r >> 16);
}
__device__ __forceinline__ float bf2f(unsigned short h) {
    union { unsigned u; float f; } v; v.u = ((unsigned)h) << 16;
    return v.f;
}

__global__ __launch_bounds__(256) void deg_kernel(const int* __restrict__ dst,
                                                  int* __restrict__ deg, int E) {
    int i = blockIdx.x * blockDim.x + threadIdx.x;
    int stride = gridDim.x * blockDim.x;
    for (; i < E; i += stride) atomicAdd(&deg[dst[i]], 1);
}

// ---- 3-kernel exclusive scan of deg -> rowptr, fused dis = rsqrt(deg+1) ----
__global__ __launch_bounds__(256) void scan_part(const int* __restrict__ deg,
                                                 int* __restrict__ bsum, int N) {
    const int t = threadIdx.x;
    const int i = blockIdx.x * SCHUNK + t * 4;
    int4 v = make_int4(0, 0, 0, 0);
    if (i + 3 < N) v = *(const int4*)(deg + i);
    else {
        if (i < N) v.x = deg[i];
        if (i + 1 < N) v.y = deg[i + 1];
        if (i + 2 < N) v.z = deg[i + 2];
    }
    int s = v.x + v.y + v.z + v.w;
#pragma unroll
    for (int d = 1; d < 64; d <<= 1) s += __shfl_xor(s, d);
    __shared__ int ws[4];
    if ((t & 63) == 0) ws[t >> 6] = s;
    __syncthreads();
    if (t == 0) bsum[blockIdx.x] = ws[0] + ws[1] + ws[2] + ws[3];
}

__global__ __launch_bounds__(128) void scan_top(int* __restrict__ bsum, int NB) {
    __shared__ int sm[128];
    const int t = threadIdx.x;
    const int v = (t < NB) ? bsum[t] : 0;
    sm[t] = v;
    __syncthreads();
    for (int d = 1; d < 128; d <<= 1) {
        int a = (t >= d) ? sm[t - d] : 0;
        __syncthreads();
        sm[t] += a;
        __syncthreads();
    }
    if (t < NB) bsum[t] = sm[t] - v;  // exclusive
}

__global__ __launch_bounds__(256) void scan_write(const int* __restrict__ deg,
                                                  const int* __restrict__ bsum,
                                                  int* __restrict__ rowptr,
                                                  float* __restrict__ dis,
                                                  int N, int NB) {
    const int t = threadIdx.x;
    const int i = blockIdx.x * SCHUNK + t * 4;
    int4 v = make_int4(0, 0, 0, 0);
    if (i + 3 < N) v = *(const int4*)(deg + i);
    else {
        if (i < N) v.x = deg[i];
        if (i + 1 < N) v.y = deg[i + 1];
        if (i + 2 < N) v.z = deg[i + 2];
    }
    const int s = v.x + v.y + v.z + v.w;
    __shared__ int sm[256];
    sm[t] = s;
    __syncthreads();
    for (int d = 1; d < 256; d <<= 1) {
        int a = (t >= d) ? sm[t - d] : 0;
        __syncthreads();
        sm[t] += a;
        __syncthreads();
    }
    int run = bsum[blockIdx.x] + sm[t] - s;
    const int dv[4] = {v.x, v.y, v.z, v.w};
#pragma unroll
    for (int j = 0; j < 4; ++j) {
        if (i + j < N) {
            rowptr[i + j] = run;
            dis[i + j] = rsqrtf((float)dv[j] + 1.0f);
        }
        run += dv[j];
    }
    if (blockIdx.x == NB - 1 && t == 255) rowptr[N] = run;  // == E
}

__global__ __launch_bounds__(256) void csr_fill(const int* __restrict__ src,
                                                const int* __restrict__ dst,
                                                const int* __restrict__ rowptr,
                                                int* __restrict__ fill,
                                                int* __restrict__ col, int E) {
    int i = blockIdx.x * blockDim.x + threadIdx.x;
    int stride = gridDim.x * blockDim.x;
    for (; i < E; i += stride) {
        const int d = dst[i];
        const int pos = rowptr[d] + atomicAdd(&fill[d], 1);
        col[pos] = src[i];
    }
}

// One-time weight pack: W [K][BN] f32 -> hi/lo bf16 in MFMA fragment order.
__global__ __launch_bounds__(256) void pack_w(const float* __restrict__ W,
                                              unsigned short* __restrict__ packH,
                                              unsigned short* __restrict__ packL,
                                              int K, int BN) {
    const int idx = blockIdx.x * blockDim.x + threadIdx.x;
    if (idx >= K * BN) return;
    const int e = idx & 7;
    const int l = (idx >> 3) & 63;
    const int rest = idx >> 9;  // ks*NF + nf
    const int NF = BN >> 4;
    const int nf = rest % NF;
    const int ks = rest / NF;
    const int n = nf * 16 + (l & 15);
    const int k = ks * 32 + ((l >> 4) & 3) * 8 + e;
    const float v = W[(size_t)k * BN + n];
    const unsigned short h = f2bf(v);
    packH[idx] = h;
    packL[idx] = f2bf(v - bf2f(h));
}

// MFMA split-bf16 GEMM: A [N][K] f32 row-major, W pre-packed fragments.
// Epilogue scales each output row by scale[row] (dis pre-scaling for agg).
template <int BN>
__global__ __launch_bounds__(256) void gemm_mfma(const float* __restrict__ A,
                                                 const unsigned short* __restrict__ WpH,
                                                 const unsigned short* __restrict__ WpL,
                                                 const float* __restrict__ scale,
                                                 float* __restrict__ Out,
                                                 int N, int K) {
    constexpr int BM = 128;
    constexpr int WROWS = (BN == 128) ? 2 : 4;
    constexpr int WCOLS = (BN == 128) ? 2 : 1;
    constexpr int WTM = BM / WROWS;
    constexpr int MF = WTM / 16;
    constexpr int NFW = (BN / WCOLS) / 16;
    constexpr int NFB = BN / 16;

    __shared__ unsigned short AsH[8][512];
    __shared__ unsigned short AsL[8][512];

    const int t = threadIdx.x;
    const int wid = t >> 6, lane = t & 63;
    const int wr = wid / WCOLS, wc = wid % WCOLS;
    const int r0 = blockIdx.x * BM;

    const int s_row1 = t >> 2;
    const int s_row2 = (t + 256) >> 2;
    const int s_kg = t & 3;
    const int s_lf = ((t >> 2) & 15) + s_kg * 16;

    f32x4 acc[MF][NFW];
#pragma unroll
    for (int m = 0; m < MF; ++m)
#pragma unroll
        for (int n = 0; n < NFW; ++n) acc[m][n] = (f32x4){0.f, 0.f, 0.f, 0.f};

    for (int k0 = 0; k0 < K; k0 += 32) {
        const int ks = k0 >> 5;
#pragma unroll
        for (int uu = 0; uu < 2; ++uu) {
            const int row = uu ? s_row2 : s_row1;
            const int gr = r0 + row;
            float4 v0 = make_float4(0.f, 0.f, 0.f, 0.f), v1 = v0;
            if (gr < N) {
                const float* ap = &A[(size_t)gr * K + k0 + s_kg * 8];
                v0 = *(const float4*)ap;
                v1 = *(const float4*)(ap + 4);
            }
            short8 h, l;
            const float vv[8] = {v0.x, v0.y, v0.z, v0.w, v1.x, v1.y, v1.z, v1.w};
#pragma unroll
            for (int j = 0; j < 8; ++j) {
                const unsigned short hh = f2bf(vv[j]);
                h[j] = (short)hh;
                l[j] = (short)f2bf(vv[j] - bf2f(hh));
            }
            const int m = row >> 4;
            *(short8*)&AsH[m][s_lf * 8] = h;
            *(short8*)&AsL[m][s_lf * 8] = l;
        }
        __syncthreads();

        short8 bH[NFW], bL[NFW];
#pragma unroll
        for (int n = 0; n < NFW; ++n) {
            const int nfg = wc * NFW + n;
            const int base = ((ks * NFB + nfg) * 64 + lane) * 8;
            bH[n] = *(const short8*)&WpH[base];
            bL[n] = *(const short8*)&WpL[base];
        }
#pragma unroll
        for (int m = 0; m < MF; ++m) {
            const int mf = wr * MF + m;
            const short8 aH = *(const short8*)&AsH[mf][lane * 8];
            const short8 aL = *(const short8*)&AsL[mf][lane * 8];
#pragma unroll
            for (int n = 0; n < NFW; ++n) {
                acc[m][n] = __builtin_amdgcn_mfma_f32_16x16x32_bf16(aH, bH[n], acc[m][n], 0, 0, 0);
                acc[m][n] = __builtin_amdgcn_mfma_f32_16x16x32_bf16(aH, bL[n], acc[m][n], 0, 0, 0);
                acc[m][n] = __builtin_amdgcn_mfma_f32_16x16x32_bf16(aL, bH[n], acc[m][n], 0, 0, 0);
            }
        }
        __syncthreads();
    }

#pragma unroll
    for (int m = 0; m < MF; ++m) {
        const int row0 = r0 + wr * WTM + m * 16 + ((lane >> 4) << 2);
        float sc[4];
#pragma unroll
        for (int r = 0; r < 4; ++r) sc[r] = (row0 + r < N) ? scale[row0 + r] : 0.f;
#pragma unroll
        for (int n = 0; n < NFW; ++n) {
            const int cn = wc * (NFW * 16) + n * 16 + (lane & 15);
#pragma unroll
            for (int r = 0; r < 4; ++r) {
                if (row0 + r < N)
                    Out[(size_t)(row0 + r) * BN + cn] = acc[m][n][r] * sc[r];
            }
        }
    }
}

// CSR gather aggregation over PRE-SCALED H' (= dis*h).
// Out[d] = relu( dis[d] * (sum_s H'[s] + H'[d]) + bias )
// NPW nodes/wave, 64/NPW lanes/node, float2/lane. Batches of 16/8 for MLP.
template <int COLS, int NPW>
__global__ __launch_bounds__(256) void agg_csr(const int* __restrict__ rowptr,
                                               const int* __restrict__ col,
                                               const float* __restrict__ dis,
                                               const float* __restrict__ Hs,
                                               const float* __restrict__ bias,
                                               float* __restrict__ Out, int N) {
    constexpr int LPN = 64 / NPW;        // lanes per node
    static_assert(COLS == LPN * 2, "float2 per lane");
    const int gw = (int)((blockIdx.x * blockDim.x + threadIdx.x) >> 6);
    const int lane = threadIdx.x & 63;
    const int sub = lane / LPN;
    const int sl = lane % LPN;
    const int lbase = sub * LPN;
    const int node = gw * NPW + sub;

    float acc0 = 0.f, acc1 = 0.f;
    int base = 0, len = 0;
    if (node < N) {
        base = rowptr[node];
        len = rowptr[node + 1] - base;
    }

    for (int j0 = 0; j0 < len; j0 += LPN) {
        const int remain = min(LPN, len - j0);
        const int sidx = (sl < remain)
                             ? __builtin_nontemporal_load(col + base + j0 + sl)
                             : 0;
        int j = 0;
        for (; j + 16 <= remain; j += 16) {
            float2 hv[16];
#pragma unroll
            for (int u = 0; u < 16; ++u) {
                const int s = __shfl(sidx, lbase + j + u);
                hv[u] = *(const float2*)(Hs + (size_t)s * COLS + sl * 2);
            }
#pragma unroll
            for (int u = 0; u < 16; ++u) {
                acc0 += hv[u].x;
                acc1 += hv[u].y;
            }
        }
        for (; j + 8 <= remain; j += 8) {
            float2 hv[8];
#pragma unroll
            for (int u = 0; u < 8; ++u) {
                const int s = __shfl(sidx, lbase + j + u);
                hv[u] = *(const float2*)(Hs + (size_t)s * COLS + sl * 2);
            }
#pragma unroll
            for (int u = 0; u < 8; ++u) {
                acc0 += hv[u].x;
                acc1 += hv[u].y;
            }
        }
        for (; j < remain; ++j) {
            const int s = __shfl(sidx, lbase + j);
            const float2 hv = *(const float2*)(Hs + (size_t)s * COLS + sl * 2);
            acc0 += hv.x;
            acc1 += hv.y;
        }
    }

    if (node < N) {
        const float dd = dis[node];
        const float2 hs = *(const float2*)(Hs + (size_t)node * COLS + sl * 2);
        const float2 bv = *(const float2*)(bias + sl * 2);
        float2 o;
        o.x = fmaxf(fmaf(acc0 + hs.x, dd, bv.x), 0.f);
        o.y = fmaxf(fmaf(acc1 + hs.y, dd, bv.y), 0.f);
        // non-temporal 8B store: don't evict Hs from cache
        union { float2 f2; double d; } u;
        u.f2 = o;
        __builtin_nontemporal_store(u.d, (double*)(Out + (size_t)node * COLS + sl * 2));
    }
}

// mean-pool prep: wave = 32 consecutive rows, lane = column.
__global__ __launch_bounds__(256) void pool_kernel(const float* __restrict__ H,
                                                   const int* __restrict__ batch,
                                                   float* __restrict__ pooled,
                                                   float* __restrict__ cnt, int N) {
    const int c = threadIdx.x & 63;
    const int w = threadIdx.x >> 6;          // wave 0..3
    const int row0 = blockIdx.x * 128 + w * 32;
    if (row0 >= N) return;
    const int nr = min(32, N - row0);

    float v[32];
    int b[32];
#pragma unroll
    for (int i = 0; i < 32; ++i) {
        const int r = row0 + i;
        if (i < nr) {
            v[i] = H[(size_t)r * 64 + c];
            b[i] = batch[r];
        } else {
            v[i] = 0.f;
            b[i] = -1;
        }
    }
    int cur = b[0];
    float sum = 0.f, csum = 0.f;
#pragma unroll
    for (int i = 0; i < 32; ++i) {
        if (i < nr) {
            if (b[i] != cur) {
                atomicAdd(&pooled[cur * 64 + c], sum);
                if (c == 0) atomicAdd(&cnt[cur], csum);
                cur = b[i];
                sum = 0.f;
                csum = 0.f;
            }
            sum += v[i];
            csum += 1.f;
        }
    }
    atomicAdd(&pooled[cur * 64 + c], sum);
    if (c == 0) atomicAdd(&cnt[cur], csum);
}

__global__ __launch_bounds__(256) void final_kernel(const float* __restrict__ pooled,
                                                    const float* __restrict__ cnt,
                                                    const float* __restrict__ Wlin,
                                                    const float* __restrict__ blin,
                                                    float* __restrict__ out) {
    const int t = threadIdx.x;
    const int g = t >> 1, o = t & 1;
    const float inv = 1.0f / fmaxf(cnt[g], 1.0f);
    float s = 0.f;
#pragma unroll
    for (int j = 0; j < 64; ++j) s = fmaf(pooled[g * 64 + j], Wlin[j * 2 + o], s);
    out[t] = s * inv + blin[o];
}

extern "C" void kernel_launch(void* const* d_in, const int* in_sizes, int n_in,
                              void* d_out, int out_size, void* d_ws, size_t ws_size,
                              hipStream_t stream) {
    const float* x     = (const float*)d_in[0];
    const int*   edge  = (const int*)d_in[1];
    const int*   batch = (const int*)d_in[2];
    const float* W1    = (const float*)d_in[3];
    const float* b1    = (const float*)d_in[4];
    const float* W2    = (const float*)d_in[5];
    const float* b2    = (const float*)d_in[6];
    const float* Wlin  = (const float*)d_in[7];
    const float* blin  = (const float*)d_in[8];
    float* out = (float*)d_out;

    const int N = NN;
    const int E = in_sizes[1] / 2;
    const int* src = edge;
    const int* dst = edge + E;
    const int NB = (N + SCHUNK - 1) / SCHUNK;  // 98

    char* ws = (char*)d_ws;
    size_t off = 0;
    auto alloc = [&](size_t bytes) -> void* {
        void* p = ws + off;
        off += (bytes + 511) & ~(size_t)511;
        return p;
    };
    int*   deg    = (int*)alloc((size_t)N * 4);
    float* dis    = (float*)alloc((size_t)N * 4);
    int*   rowptr = (int*)alloc((size_t)(N + 1) * 4);
    int*   fill   = (int*)alloc((size_t)N * 4);
    int*   bsum   = (int*)alloc((size_t)NB * 4);
    int*   col    = (int*)alloc((size_t)E * 4);
    unsigned short* w1h = (unsigned short*)alloc((size_t)384 * 128 * 2);
    unsigned short* w1l = (unsigned short*)alloc((size_t)384 * 128 * 2);
    unsigned short* w2h = (unsigned short*)alloc((size_t)128 * 64 * 2);
    unsigned short* w2l = (unsigned short*)alloc((size_t)128 * 64 * 2);
    float* h1     = (float*)alloc((size_t)N * 128 * 4);
    float* agg1   = (float*)alloc((size_t)N * 128 * 4);
    float* pooled = (float*)alloc((size_t)NG * 64 * 4);
    float* cnt    = (float*)alloc((size_t)NG * 4);
    float* h2   = h1;
    float* agg2 = (float*)((char*)h1 + (size_t)N * 64 * 4);

    hipMemsetAsync(deg, 0, (size_t)N * 4, stream);
    hipMemsetAsync(fill, 0, (size_t)N * 4, stream);
    hipMemsetAsync(pooled, 0, (size_t)NG * 64 * 4, stream);
    hipMemsetAsync(cnt, 0, (size_t)NG * 4, stream);

    // weight packing (tiny, once per call)
    pack_w<<<(384 * 128 + 255) / 256, 256, 0, stream>>>(W1, w1h, w1l, 384, 128);
    pack_w<<<(128 * 64 + 255) / 256, 256, 0, stream>>>(W2, w2h, w2l, 128, 64);

    // degree + CSR build + normalization
    deg_kernel<<<2048, 256, 0, stream>>>(dst, deg, E);
    scan_part<<<NB, 256, 0, stream>>>(deg, bsum, N);
    scan_top<<<1, 128, 0, stream>>>(bsum, NB);
    scan_write<<<NB, 256, 0, stream>>>(deg, bsum, rowptr, dis, N, NB);
    csr_fill<<<2048, 256, 0, stream>>>(src, dst, rowptr, fill, col, E);

    const int gblocks = (N + 127) / 128;
    // layer 1 (gemm writes dis-prescaled h1')
    gemm_mfma<128><<<gblocks, 256, 0, stream>>>(x, w1h, w1l, dis, h1, N, 384);
    agg_csr<128, 1><<<(N + 3) / 4, 256, 0, stream>>>(rowptr, col, dis, h1, b1, agg1, N);

    // layer 2 (h2' = dis * (agg1 @ W2), into h1's region)
    gemm_mfma<64><<<gblocks, 256, 0, stream>>>(agg1, w2h, w2l, dis, h2, N, 128);
    agg_csr<64, 2><<<(N + 7) / 8, 256, 0, stream>>>(rowptr, col, dis, h2, b2, agg2, N);

    // pool + head
    pool_kernel<<<(N + 127) / 128, 256, 0, stream>>>(agg2, batch, pooled, cnt, N);
    final_kernel<<<1, 256, 0, stream>>>(pooled, cnt, Wlin, blin, out);
}